// Round 11
// baseline (525.041 us; speedup 1.0000x reference)
//
#include <hip/hip_runtime.h>

#define N_NODES 100000
#define N_EDGES 1600000
#define N_GRAPHS 256
#define HID 128
#define BN_EPS 1e-5f

#define NT 1563        // ceil(N_NODES/64) tile buckets
#define EB 4096        // edges per reorder block
#define RB 391         // ceil(N_EDGES/EB)
#define PB 3125        // mlp wave-blocks (32 rows each), 3125*32 = 100000 exact

typedef __bf16 bf16x8 __attribute__((ext_vector_type(8)));
typedef __bf16 bf16x4 __attribute__((ext_vector_type(4)));
typedef __bf16 bf16x2 __attribute__((ext_vector_type(2)));
typedef float f32x4 __attribute__((ext_vector_type(4)));

// ---- fused setup: x->bf16, weight prep, per-graph counts, tile histogram ---
__global__ __launch_bounds__(256) void setup_kernel(
    const float* __restrict__ x, __bf16* __restrict__ xb,
    const float* __restrict__ wa, const float* __restrict__ wb,
    const float* __restrict__ wc, const float* __restrict__ wd,
    const float* __restrict__ we, const float* __restrict__ wf,
    __bf16* __restrict__ wt,
    const int* __restrict__ batch, int* __restrict__ counts,
    const int* __restrict__ ei, int* __restrict__ tcnt) {
  __shared__ int hist[NT];
  int b = blockIdx.x;
  if (b < 6250) {  // x convert: chunks of 4 floats
    int idx = b * 256 + threadIdx.x;
    if (idx >= N_NODES * 16) return;
    f32x4 v = ((const f32x4*)x)[idx];
    bf16x4 o = {(__bf16)v[0], (__bf16)v[1], (__bf16)v[2], (__bf16)v[3]};
    ((bf16x4*)xb)[idx] = o;
  } else if (b < 6250 + 352) {  // weight prep
    int idx = (b - 6250) * 256 + threadIdx.x;
    if (idx >= 90112) return;
    const float* w;
    int K, local;
    if (idx < 8192) { w = wa; K = 64; local = idx; }
    else {
      int s = (idx - 8192) / 16384;
      local = (idx - 8192) - s * 16384;
      K = 128;
      w = (s == 0) ? wb : (s == 1) ? wc : (s == 2) ? wd : (s == 3) ? we : wf;
    }
    int n = local / K, k = local - n * K;
    wt[idx] = (__bf16)w[k * 128 + n];
  } else if (b < 6609) {  // per-graph node counts (batch is sorted)
    int t = (b - 6602) * 256 + threadIdx.x;
    int r0 = t * 64;
    if (r0 >= N_NODES) return;
    int rend = min(r0 + 64, N_NODES);
    int curg = batch[r0], cnt = 0;
    for (int r = r0; r < rend; r++) {
      int g = batch[r];
      if (g != curg) {
        atomicAdd(&counts[curg], cnt);
        curg = g;
        cnt = 1;
      } else {
        cnt++;
      }
    }
    atomicAdd(&counts[curg], cnt);
  } else {  // tile histogram (391 blocks)
    int t = threadIdx.x;
    for (int i = t; i < NT; i += 256) hist[i] = 0;
    __syncthreads();
    int base = (b - 6609) * EB;
#pragma unroll 4
    for (int i = 0; i < EB / 256; i++) {
      int e = base + i * 256 + t;
      if (e < N_EDGES) atomicAdd(&hist[ei[N_EDGES + e] >> 6], 1);
    }
    __syncthreads();
    for (int i = t; i < NT; i += 256) {
      int h = hist[i];
      if (h) atomicAdd(&tcnt[i], h);
    }
  }
}

// ---------------- CSR stage 2: scan 1563 tile counts ------------------------
__global__ __launch_bounds__(256) void tile_scan_kernel(const int* __restrict__ tcnt,
                                                        int* __restrict__ tstart,
                                                        int* __restrict__ gcursor) {
  __shared__ int ps[256];
  int t = threadIdx.x;
  const int CH = (NT + 255) / 256;  // 7
  int lo = t * CH, hi = min(lo + CH, NT);
  int s = 0;
  for (int i = lo; i < hi; i++) s += tcnt[i];
  ps[t] = s;
  __syncthreads();
  for (int off = 1; off < 256; off <<= 1) {
    int v = ps[t];
    int u = (t >= off) ? ps[t - off] : 0;
    __syncthreads();
    ps[t] = v + u;
    __syncthreads();
  }
  int base = (t == 0) ? 0 : ps[t - 1];
  for (int i = lo; i < hi; i++) {
    tstart[i] = base;
    gcursor[i] = base;
    base += tcnt[i];
  }
  if (t == 0) tstart[NT] = N_EDGES;
}

// ---------------- CSR stage 3: scatter into tile buckets (local writes) -----
__global__ __launch_bounds__(256) void reorder2_kernel(const int* __restrict__ ei,
                                                       int* __restrict__ gcursor,
                                                       int* __restrict__ epack) {
  __shared__ int hist[NT];
  int t = threadIdx.x;
  for (int i = t; i < NT; i += 256) hist[i] = 0;
  __syncthreads();
  int base = blockIdx.x * EB;
#pragma unroll 4
  for (int i = 0; i < EB / 256; i++) {
    int e = base + i * 256 + t;
    if (e < N_EDGES) atomicAdd(&hist[ei[N_EDGES + e] >> 6], 1);
  }
  __syncthreads();
  for (int i = t; i < NT; i += 256) {
    int h = hist[i];
    if (h) hist[i] = atomicAdd(&gcursor[i], h);
  }
  __syncthreads();
#pragma unroll 4
  for (int i = 0; i < EB / 256; i++) {
    int e = base + i * 256 + t;
    if (e < N_EDGES) {
      int d = ei[N_EDGES + e];
      int s = ei[e];
      int pos = atomicAdd(&hist[d >> 6], 1);
      epack[pos] = (s << 6) | (d & 63);
    }
  }
}

// ---------------- CSR stage 4: per-tile counting sort -> row CSR ------------
__global__ __launch_bounds__(256) void row_sort_kernel(const int* __restrict__ tstart,
                                                       const int* __restrict__ epack,
                                                       int* __restrict__ starts,
                                                       int* __restrict__ srcs) {
  __shared__ int cnt[64];
  __shared__ int rbase[65];
  __shared__ int rofs[64];
  int t = threadIdx.x, b = blockIdx.x;
  int ts = tstart[b], te = tstart[b + 1];
  if (t < 64) cnt[t] = 0;
  __syncthreads();
  for (int i = ts + t; i < te; i += 256) atomicAdd(&cnt[epack[i] & 63], 1);
  __syncthreads();
  if (t == 0) {
    int a = 0;
    for (int r = 0; r < 64; r++) { rbase[r] = a; a += cnt[r]; }
    rbase[64] = a;
  }
  __syncthreads();
  if (t < 64) rofs[t] = ts + rbase[t];
  if (t <= 64) {
    int gr = b * 64 + t;
    if (gr <= N_NODES) starts[gr] = ts + rbase[t];
  }
  __syncthreads();
  for (int i = ts + t; i < te; i += 256) {
    int p = epack[i];
    int pos = atomicAdd(&rofs[p & 63], 1);
    srcs[pos] = p >> 6;
  }
}

// ---------------- gather (+ fused BN finalize-and-apply on inputs) ----------
// z[row] = h(row) + sum_{CSR[row]} h(src),  h(v) = BN ? relu(a*v+b) : v
// Scalar-path edge loop (row uniform via readfirstlane -> srcs via s_load).
template <int C, bool BN>
__global__ __launch_bounds__(256) void gather_kernel(const __bf16* __restrict__ h,
                                                     const float* __restrict__ accum,
                                                     const float* __restrict__ gamma,
                                                     const float* __restrict__ beta,
                                                     const int* __restrict__ starts,
                                                     const int* __restrict__ srcs,
                                                     __bf16* __restrict__ z) {
  const int lane = threadIdx.x & 63;
  const int row = __builtin_amdgcn_readfirstlane(blockIdx.x * 4 + (threadIdx.x >> 6));
  const int e0 = starts[row], e1 = starts[row + 1];

  if constexpr (C == 128) {
    float a0 = 0.f, a1 = 0.f, b0 = 0.f, b1 = 0.f;
    if constexpr (BN) {
      const int c0 = lane * 2, c1 = c0 + 1;
      const float invN = 1.f / (float)N_NODES;
      float m0 = accum[c0] * invN, m1 = accum[c1] * invN;
      float v0 = accum[HID + c0] * invN - m0 * m0;
      float v1 = accum[HID + c1] * invN - m1 * m1;
      a0 = gamma[c0] * rsqrtf(v0 + BN_EPS);
      a1 = gamma[c1] * rsqrtf(v1 + BN_EPS);
      b0 = beta[c0] - m0 * a0;
      b1 = beta[c1] - m1 * a1;
    }
#define ACCBN(vv, ss)                                                  \
    do {                                                               \
      if constexpr (BN) {                                              \
        ss.x += fmaxf(fmaf(a0, (float)(vv)[0], b0), 0.f);              \
        ss.y += fmaxf(fmaf(a1, (float)(vv)[1], b1), 0.f);              \
      } else {                                                         \
        ss.x += (float)(vv)[0];                                        \
        ss.y += (float)(vv)[1];                                        \
      }                                                                \
    } while (0)
    float2 s0 = {0.f, 0.f}, s1 = {0.f, 0.f}, s2 = {0.f, 0.f}, s3 = {0.f, 0.f};
    float2 s4 = {0.f, 0.f}, s5 = {0.f, 0.f}, s6 = {0.f, 0.f}, s7 = {0.f, 0.f};
    int e = e0;
    for (; e + 7 < e1; e += 8) {
      int i0 = srcs[e];      // uniform -> s_load
      int i1 = srcs[e + 1];
      int i2 = srcs[e + 2];
      int i3 = srcs[e + 3];
      int i4 = srcs[e + 4];
      int i5 = srcs[e + 5];
      int i6 = srcs[e + 6];
      int i7 = srcs[e + 7];
      bf16x2 v0 = *(const bf16x2*)(h + (size_t)i0 * 128 + lane * 2);
      bf16x2 v1 = *(const bf16x2*)(h + (size_t)i1 * 128 + lane * 2);
      bf16x2 v2 = *(const bf16x2*)(h + (size_t)i2 * 128 + lane * 2);
      bf16x2 v3 = *(const bf16x2*)(h + (size_t)i3 * 128 + lane * 2);
      bf16x2 v4 = *(const bf16x2*)(h + (size_t)i4 * 128 + lane * 2);
      bf16x2 v5 = *(const bf16x2*)(h + (size_t)i5 * 128 + lane * 2);
      bf16x2 v6 = *(const bf16x2*)(h + (size_t)i6 * 128 + lane * 2);
      bf16x2 v7 = *(const bf16x2*)(h + (size_t)i7 * 128 + lane * 2);
      ACCBN(v0, s0);
      ACCBN(v1, s1);
      ACCBN(v2, s2);
      ACCBN(v3, s3);
      ACCBN(v4, s4);
      ACCBN(v5, s5);
      ACCBN(v6, s6);
      ACCBN(v7, s7);
    }
    for (; e + 3 < e1; e += 4) {
      int i0 = srcs[e];
      int i1 = srcs[e + 1];
      int i2 = srcs[e + 2];
      int i3 = srcs[e + 3];
      bf16x2 v0 = *(const bf16x2*)(h + (size_t)i0 * 128 + lane * 2);
      bf16x2 v1 = *(const bf16x2*)(h + (size_t)i1 * 128 + lane * 2);
      bf16x2 v2 = *(const bf16x2*)(h + (size_t)i2 * 128 + lane * 2);
      bf16x2 v3 = *(const bf16x2*)(h + (size_t)i3 * 128 + lane * 2);
      ACCBN(v0, s0);
      ACCBN(v1, s1);
      ACCBN(v2, s2);
      ACCBN(v3, s3);
    }
    for (; e < e1; e++) {
      int i0 = srcs[e];
      bf16x2 vv = *(const bf16x2*)(h + (size_t)i0 * 128 + lane * 2);
      ACCBN(vv, s0);
    }
    bf16x2 sv = *(const bf16x2*)(h + (size_t)row * 128 + lane * 2);
    ACCBN(sv, s0);
    float tx = ((s0.x + s1.x) + (s2.x + s3.x)) + ((s4.x + s5.x) + (s6.x + s7.x));
    float ty = ((s0.y + s1.y) + (s2.y + s3.y)) + ((s4.y + s5.y) + (s6.y + s7.y));
    bf16x2 o = {(__bf16)tx, (__bf16)ty};
    *(bf16x2*)(z + (size_t)row * 128 + lane * 2) = o;
#undef ACCBN
  } else {  // C == 64 (layer 0, no BN)
    float s0 = 0.f, s1 = 0.f, s2 = 0.f, s3 = 0.f;
    float s4 = 0.f, s5 = 0.f, s6 = 0.f, s7 = 0.f;
    int e = e0;
    for (; e + 7 < e1; e += 8) {
      int i0 = srcs[e];
      int i1 = srcs[e + 1];
      int i2 = srcs[e + 2];
      int i3 = srcs[e + 3];
      int i4 = srcs[e + 4];
      int i5 = srcs[e + 5];
      int i6 = srcs[e + 6];
      int i7 = srcs[e + 7];
      s0 += (float)h[(size_t)i0 * 64 + lane];
      s1 += (float)h[(size_t)i1 * 64 + lane];
      s2 += (float)h[(size_t)i2 * 64 + lane];
      s3 += (float)h[(size_t)i3 * 64 + lane];
      s4 += (float)h[(size_t)i4 * 64 + lane];
      s5 += (float)h[(size_t)i5 * 64 + lane];
      s6 += (float)h[(size_t)i6 * 64 + lane];
      s7 += (float)h[(size_t)i7 * 64 + lane];
    }
    for (; e + 3 < e1; e += 4) {
      int i0 = srcs[e];
      int i1 = srcs[e + 1];
      int i2 = srcs[e + 2];
      int i3 = srcs[e + 3];
      s0 += (float)h[(size_t)i0 * 64 + lane];
      s1 += (float)h[(size_t)i1 * 64 + lane];
      s2 += (float)h[(size_t)i2 * 64 + lane];
      s3 += (float)h[(size_t)i3 * 64 + lane];
    }
    for (; e < e1; e++) {
      int i0 = srcs[e];
      s0 += (float)h[(size_t)i0 * 64 + lane];
    }
    s0 += (float)h[(size_t)row * 64 + lane];
    float tot = ((s0 + s1) + (s2 + s3)) + ((s4 + s5) + (s6 + s7));
    z[(size_t)row * 64 + lane] = (__bf16)tot;
  }
}

// ---------------- 1-wave 32-row MLP: weight reuse x2, high occupancy --------
// M=32/wave: acc[8][2]=64 VGPR (<=128 with launch_bounds(64,4) -> 4 waves/
// SIMD eligible); grid 3125 blocks -> ~12 blocks/CU, 2x the resident waves of
// the M=64 version. Weight traffic 200 MB L2/dispatch (slack). 100000=3125*32
// exactly: no clamps, no tails. Wave-private 32x136 LDS tile, no barriers.
template <int CIN>
__global__ __launch_bounds__(64, 4) void mlp_kernel(
    const __bf16* __restrict__ z, const __bf16* __restrict__ w1t,
    const float* __restrict__ b1, const __bf16* __restrict__ w2t,
    const float* __restrict__ b2, __bf16* __restrict__ u,
    float* __restrict__ part) {
  constexpr int TS = HID + 8;  // 136 row stride
  __shared__ __align__(16) __bf16 sm[32 * TS];  // 8704 B

  const int lane = threadIdx.x;
  const int l16 = lane & 15;
  const int quad = lane >> 4;
  const int rowbase = blockIdx.x * 32;

  const f32x4 zero4 = {0.f, 0.f, 0.f, 0.f};
  f32x4 acc[8][2];

  // GEMM1: t1 = relu(z @ W1 + b1) -> LDS tile
  {
#pragma unroll
    for (int ct = 0; ct < 8; ct++)
#pragma unroll
      for (int m = 0; m < 2; m++) acc[ct][m] = zero4;
#pragma unroll
    for (int ks = 0; ks < CIN / 32; ks++) {
      bf16x8 af[2];
#pragma unroll
      for (int m = 0; m < 2; m++)
        af[m] = *(const bf16x8*)(z + (size_t)(rowbase + m * 16 + l16) * CIN + ks * 32 + quad * 8);
#pragma unroll
      for (int ct = 0; ct < 8; ct++) {
        bf16x8 bfr = *(const bf16x8*)(w1t + (ct * 16 + l16) * CIN + ks * 32 + quad * 8);
#pragma unroll
        for (int m = 0; m < 2; m++)
          acc[ct][m] = __builtin_amdgcn_mfma_f32_16x16x32_bf16(af[m], bfr, acc[ct][m], 0, 0, 0);
      }
    }
#pragma unroll
    for (int ct = 0; ct < 8; ct++) {
      int col = ct * 16 + l16;
      float bias = b1[col];
#pragma unroll
      for (int m = 0; m < 2; m++)
#pragma unroll
        for (int r = 0; r < 4; r++) {
          float v = acc[ct][m][r] + bias;
          sm[(m * 16 + quad * 4 + r) * TS + col] = (__bf16)(v > 0.f ? v : 0.f);
        }
    }
  }

  // GEMM2: u = t1 @ W2 + b2 (in-wave LDS ordering via lgkmcnt)
  {
#pragma unroll
    for (int ct = 0; ct < 8; ct++)
#pragma unroll
      for (int m = 0; m < 2; m++) acc[ct][m] = zero4;
#pragma unroll
    for (int ks = 0; ks < HID / 32; ks++) {
      bf16x8 af[2];
#pragma unroll
      for (int m = 0; m < 2; m++)
        af[m] = *(const bf16x8*)(sm + (m * 16 + l16) * TS + ks * 32 + quad * 8);
#pragma unroll
      for (int ct = 0; ct < 8; ct++) {
        bf16x8 bfr = *(const bf16x8*)(w2t + (ct * 16 + l16) * HID + ks * 32 + quad * 8);
#pragma unroll
        for (int m = 0; m < 2; m++)
          acc[ct][m] = __builtin_amdgcn_mfma_f32_16x16x32_bf16(af[m], bfr, acc[ct][m], 0, 0, 0);
      }
    }
  }

  // epilogue: acc -> LDS (bf16), then coalesced store + BN partials from LDS
#pragma unroll
  for (int ct = 0; ct < 8; ct++) {
    int col = ct * 16 + l16;
    float bias = b2[col];
#pragma unroll
    for (int m = 0; m < 2; m++)
#pragma unroll
      for (int r = 0; r < 4; r++)
        sm[(m * 16 + quad * 4 + r) * TS + col] = (__bf16)(acc[ct][m][r] + bias);
  }

  // coalesced bf16x8 store of the 32 rows
  for (int f = lane; f < 32 * 16; f += 64) {
    int r = f >> 4, c8 = f & 15;
    bf16x8 v = *(const bf16x8*)(sm + r * TS + c8 * 8);
    *(bf16x8*)(u + (size_t)(rowbase + r) * HID + c8 * 8) = v;
  }

  // BN partials: lane owns columns 2*lane, 2*lane+1 -> coalesced part rows
  {
    float s0 = 0.f, q0 = 0.f, s1 = 0.f, q1 = 0.f;
    for (int r = 0; r < 32; r++) {
      bf16x2 v = *(const bf16x2*)(sm + r * TS + lane * 2);
      float f0 = (float)v[0], f1 = (float)v[1];
      s0 += f0; q0 += f0 * f0;
      s1 += f1; q1 += f1 * f1;
    }
    float2 sp = {s0, s1}, qp = {q0, q1};
    *(float2*)(part + (size_t)blockIdx.x * 256 + lane * 2) = sp;
    *(float2*)(part + (size_t)blockIdx.x * 256 + HID + lane * 2) = qp;
  }
}

// ---------------- part (PB x 256, coalesced) -> accum[256] via atomics ------
__global__ __launch_bounds__(256) void reduce_part_kernel(const float* __restrict__ part,
                                                          float* __restrict__ accum) {
  int t = threadIdx.x;
  float s = 0.f;
  for (int r = blockIdx.x; r < PB; r += gridDim.x)
    s += part[(size_t)r * 256 + t];
  atomicAdd(&accum[t], s);
}

// ---------------- BN finalize+apply + mean-pool accumulate (layer 2) --------
__global__ __launch_bounds__(128) void bn_apply_pool_kernel(const __bf16* __restrict__ u,
                                                            const float* __restrict__ accum,
                                                            const float* __restrict__ gamma,
                                                            const float* __restrict__ beta,
                                                            const int* __restrict__ batch,
                                                            float* __restrict__ pool) {
  int c = threadIdx.x;  // feature column
  int r0 = blockIdx.x * 64;
  if (r0 >= N_NODES) return;
  int rend = min(r0 + 64, N_NODES);
  const float invN = 1.f / (float)N_NODES;
  float mean = accum[c] * invN;
  float var = accum[HID + c] * invN - mean * mean;
  float a = gamma[c] * rsqrtf(var + BN_EPS);
  float b = beta[c] - mean * a;
  float accv = 0.f;
  int curg = -1;
  for (int r = r0; r < rend; r++) {
    int g = batch[r];
    if (g != curg) {
      if (curg >= 0) atomicAdd(&pool[curg * HID + c], accv);
      curg = g;
      accv = 0.f;
    }
    float v = (float)u[(size_t)r * HID + c];
    v = v * a + b;
    accv += (v > 0.f ? v : 0.f);
  }
  if (curg >= 0) atomicAdd(&pool[curg * HID + c], accv);
}

// ---------------- hg = pool/cnt; out = hg @ proj_w + proj_b -----------------
__global__ __launch_bounds__(128) void pool_proj_kernel(const float* __restrict__ pool,
                                                        const int* __restrict__ counts,
                                                        const float* __restrict__ pw,
                                                        const float* __restrict__ pb,
                                                        float* __restrict__ out) {
  int g = blockIdx.x;
  int c = threadIdx.x;
  __shared__ float hg[HID];
  float cnt = (float)max(counts[g], 1);
  hg[c] = pool[g * HID + c] / cnt;
  __syncthreads();
  float acc = pb[c];
#pragma unroll 8
  for (int k = 0; k < HID; k++) acc += hg[k] * pw[k * HID + c];
  out[g * HID + c] = acc;
}

// ============================================================================
extern "C" void kernel_launch(void* const* d_in, const int* in_sizes, int n_in,
                              void* d_out, int out_size, void* d_ws, size_t ws_size,
                              hipStream_t stream) {
  (void)in_sizes; (void)n_in; (void)out_size; (void)ws_size;
  const float* x = (const float*)d_in[0];
  const int* ei = (const int*)d_in[1];
  const int* batch = (const int*)d_in[2];
  const float* w1[3] = {(const float*)d_in[3], (const float*)d_in[9], (const float*)d_in[15]};
  const float* b1[3] = {(const float*)d_in[4], (const float*)d_in[10], (const float*)d_in[16]};
  const float* w2[3] = {(const float*)d_in[5], (const float*)d_in[11], (const float*)d_in[17]};
  const float* b2[3] = {(const float*)d_in[6], (const float*)d_in[12], (const float*)d_in[18]};
  const float* gm[3] = {(const float*)d_in[7], (const float*)d_in[13], (const float*)d_in[19]};
  const float* bt[3] = {(const float*)d_in[8], (const float*)d_in[14], (const float*)d_in[20]};
  const float* pw = (const float*)d_in[21];
  const float* pb = (const float*)d_in[22];
  float* out = (float*)d_out;

  // workspace carve
  char* ws = (char*)d_ws;
  __bf16* bufA = (__bf16*)ws;        ws += (size_t)N_NODES * HID * 2;   // 25.6 MB
  __bf16* bufB = (__bf16*)ws;        ws += (size_t)N_NODES * HID * 2;   // 25.6 MB
  __bf16* bufC = (__bf16*)ws;        ws += (size_t)N_NODES * HID * 2;   // 25.6 MB (z scratch)
  __bf16* z0 = (__bf16*)ws;          ws += (size_t)N_NODES * 64 * 2;    // 12.8 MB (layer-0 z)
  __bf16* xb = (__bf16*)ws;          ws += (size_t)N_NODES * 64 * 2;    // 12.8 MB
  int* srcs = (int*)ws;              ws += (size_t)N_EDGES * 4;         // 6.4 MB
  int* epack = (int*)ws;             ws += (size_t)N_EDGES * 4;         // 6.4 MB
  int* starts = (int*)ws;            ws += (size_t)(N_NODES + 1) * 4;
  int* tcnt = (int*)ws;              ws += NT * 4;
  int* tstart = (int*)ws;            ws += (NT + 1) * 4;
  int* gcursor = (int*)ws;           ws += NT * 4;
  ws = (char*)(((uintptr_t)ws + 63) & ~(uintptr_t)63);
  float* part = (float*)ws;          ws += (size_t)PB * 256 * 4;        // 3.2 MB
  __bf16* wt_all = (__bf16*)ws;      ws += 90112 * 2;
  ws = (char*)(((uintptr_t)ws + 63) & ~(uintptr_t)63);
  float* accum = (float*)ws;         ws += 3 * 256 * 4;                 // s,sq per layer
  float* pool = (float*)ws;          ws += N_GRAPHS * HID * 4;          // contiguous w/ accum
  int* counts = (int*)ws;            ws += N_GRAPHS * 4;                // and counts

  __bf16* w1t0 = wt_all;
  __bf16* w2t0 = wt_all + 8192;
  __bf16* w1t1 = wt_all + 24576;
  __bf16* w2t1 = wt_all + 40960;
  __bf16* w1t2 = wt_all + 57344;
  __bf16* w2t2 = wt_all + 73728;

  float* acc0 = accum;
  float* acc1 = accum + 256;
  float* acc2 = accum + 512;

  const int gat_blocks = (N_NODES + 3) / 4;  // 25000

  // zero accum + pool + counts (contiguous) and tcnt FIRST
  hipMemsetAsync(accum, 0, 3 * 256 * 4 + (size_t)N_GRAPHS * HID * 4 + N_GRAPHS * 4, stream);
  hipMemsetAsync(tcnt, 0, NT * 4, stream);

  // fused setup: x->bf16 (6250) + weights (352) + counts (7) + tile hist (391)
  setup_kernel<<<7000, 256, 0, stream>>>(x, xb, w1[0], w2[0], w1[1], w2[1],
                                         w1[2], w2[2], wt_all, batch, counts, ei, tcnt);

  // CSR build: tile scan -> tile-bucket scatter -> per-tile sort
  tile_scan_kernel<<<1, 256, 0, stream>>>(tcnt, tstart, gcursor);
  reorder2_kernel<<<RB, 256, 0, stream>>>(ei, gcursor, epack);
  row_sort_kernel<<<NT, 256, 0, stream>>>(tstart, epack, starts, srcs);

  // layer 0: gather(xb) -> z0; mlp64 -> bufA (u0) + part; reduce
  gather_kernel<64, false><<<gat_blocks, 256, 0, stream>>>(xb, nullptr, nullptr, nullptr,
                                                           starts, srcs, z0);
  mlp_kernel<64><<<PB, 64, 0, stream>>>(z0, w1t0, b1[0], w2t0, b2[0], bufA, part);
  reduce_part_kernel<<<128, 256, 0, stream>>>(part, acc0);

  // layer 1: BN(acc0)-relu-gather(u0) -> bufC; mlp -> bufB (u1); reduce
  gather_kernel<128, true><<<gat_blocks, 256, 0, stream>>>(bufA, acc0, gm[0], bt[0],
                                                           starts, srcs, bufC);
  mlp_kernel<128><<<PB, 64, 0, stream>>>(bufC, w1t1, b1[1], w2t1, b2[1], bufB, part);
  reduce_part_kernel<<<128, 256, 0, stream>>>(part, acc1);

  // layer 2: BN(acc1)-relu-gather(u1) -> bufC; mlp -> bufA (u2); reduce
  gather_kernel<128, true><<<gat_blocks, 256, 0, stream>>>(bufB, acc1, gm[1], bt[1],
                                                           starts, srcs, bufC);
  mlp_kernel<128><<<PB, 64, 0, stream>>>(bufC, w1t2, b1[2], w2t2, b2[2], bufA, part);
  reduce_part_kernel<<<128, 256, 0, stream>>>(part, acc2);

  bn_apply_pool_kernel<<<NT, 128, 0, stream>>>(bufA, acc2, gm[2], bt[2], batch, pool);

  pool_proj_kernel<<<N_GRAPHS, 128, 0, stream>>>(pool, counts, pw, pb, out);
}

// Round 12
// 487.839 us; speedup vs baseline: 1.0763x; 1.0763x over previous
//
#include <hip/hip_runtime.h>

#define N_NODES 100000
#define N_EDGES 1600000
#define N_GRAPHS 256
#define HID 128
#define BN_EPS 1e-5f

#define NT 1563        // ceil(N_NODES/64) tile buckets
#define EB 4096        // edges per reorder block
#define RB 391         // ceil(N_EDGES/EB)
#define MBLK 391       // mlp blocks (4 waves x 64 rows = 256 rows), 391*256 = 100096
#define PB 1564        // part rows = MBLK*4 waves

typedef __bf16 bf16x8 __attribute__((ext_vector_type(8)));
typedef __bf16 bf16x4 __attribute__((ext_vector_type(4)));
typedef __bf16 bf16x2 __attribute__((ext_vector_type(2)));
typedef float f32x4 __attribute__((ext_vector_type(4)));

// ---- fused setup: x->bf16, weight prep, per-graph counts, tile histogram ---
__global__ __launch_bounds__(256) void setup_kernel(
    const float* __restrict__ x, __bf16* __restrict__ xb,
    const float* __restrict__ wa, const float* __restrict__ wb,
    const float* __restrict__ wc, const float* __restrict__ wd,
    const float* __restrict__ we, const float* __restrict__ wf,
    __bf16* __restrict__ wt,
    const int* __restrict__ batch, int* __restrict__ counts,
    const int* __restrict__ ei, int* __restrict__ tcnt) {
  __shared__ int hist[NT];
  int b = blockIdx.x;
  if (b < 6250) {  // x convert: chunks of 4 floats
    int idx = b * 256 + threadIdx.x;
    if (idx >= N_NODES * 16) return;
    f32x4 v = ((const f32x4*)x)[idx];
    bf16x4 o = {(__bf16)v[0], (__bf16)v[1], (__bf16)v[2], (__bf16)v[3]};
    ((bf16x4*)xb)[idx] = o;
  } else if (b < 6250 + 352) {  // weight prep
    int idx = (b - 6250) * 256 + threadIdx.x;
    if (idx >= 90112) return;
    const float* w;
    int K, local;
    if (idx < 8192) { w = wa; K = 64; local = idx; }
    else {
      int s = (idx - 8192) / 16384;
      local = (idx - 8192) - s * 16384;
      K = 128;
      w = (s == 0) ? wb : (s == 1) ? wc : (s == 2) ? wd : (s == 3) ? we : wf;
    }
    int n = local / K, k = local - n * K;
    wt[idx] = (__bf16)w[k * 128 + n];
  } else if (b < 6609) {  // per-graph node counts (batch is sorted)
    int t = (b - 6602) * 256 + threadIdx.x;
    int r0 = t * 64;
    if (r0 >= N_NODES) return;
    int rend = min(r0 + 64, N_NODES);
    int curg = batch[r0], cnt = 0;
    for (int r = r0; r < rend; r++) {
      int g = batch[r];
      if (g != curg) {
        atomicAdd(&counts[curg], cnt);
        curg = g;
        cnt = 1;
      } else {
        cnt++;
      }
    }
    atomicAdd(&counts[curg], cnt);
  } else {  // tile histogram (391 blocks)
    int t = threadIdx.x;
    for (int i = t; i < NT; i += 256) hist[i] = 0;
    __syncthreads();
    int base = (b - 6609) * EB;
#pragma unroll 4
    for (int i = 0; i < EB / 256; i++) {
      int e = base + i * 256 + t;
      if (e < N_EDGES) atomicAdd(&hist[ei[N_EDGES + e] >> 6], 1);
    }
    __syncthreads();
    for (int i = t; i < NT; i += 256) {
      int h = hist[i];
      if (h) atomicAdd(&tcnt[i], h);
    }
  }
}

// ---------------- CSR stage 2: scan 1563 tile counts ------------------------
__global__ __launch_bounds__(256) void tile_scan_kernel(const int* __restrict__ tcnt,
                                                        int* __restrict__ tstart,
                                                        int* __restrict__ gcursor) {
  __shared__ int ps[256];
  int t = threadIdx.x;
  const int CH = (NT + 255) / 256;  // 7
  int lo = t * CH, hi = min(lo + CH, NT);
  int s = 0;
  for (int i = lo; i < hi; i++) s += tcnt[i];
  ps[t] = s;
  __syncthreads();
  for (int off = 1; off < 256; off <<= 1) {
    int v = ps[t];
    int u = (t >= off) ? ps[t - off] : 0;
    __syncthreads();
    ps[t] = v + u;
    __syncthreads();
  }
  int base = (t == 0) ? 0 : ps[t - 1];
  for (int i = lo; i < hi; i++) {
    tstart[i] = base;
    gcursor[i] = base;
    base += tcnt[i];
  }
  if (t == 0) tstart[NT] = N_EDGES;
}

// ---------------- CSR stage 3: scatter into tile buckets (local writes) -----
__global__ __launch_bounds__(256) void reorder2_kernel(const int* __restrict__ ei,
                                                       int* __restrict__ gcursor,
                                                       int* __restrict__ epack) {
  __shared__ int hist[NT];
  int t = threadIdx.x;
  for (int i = t; i < NT; i += 256) hist[i] = 0;
  __syncthreads();
  int base = blockIdx.x * EB;
#pragma unroll 4
  for (int i = 0; i < EB / 256; i++) {
    int e = base + i * 256 + t;
    if (e < N_EDGES) atomicAdd(&hist[ei[N_EDGES + e] >> 6], 1);
  }
  __syncthreads();
  for (int i = t; i < NT; i += 256) {
    int h = hist[i];
    if (h) hist[i] = atomicAdd(&gcursor[i], h);
  }
  __syncthreads();
#pragma unroll 4
  for (int i = 0; i < EB / 256; i++) {
    int e = base + i * 256 + t;
    if (e < N_EDGES) {
      int d = ei[N_EDGES + e];
      int s = ei[e];
      int pos = atomicAdd(&hist[d >> 6], 1);
      epack[pos] = (s << 6) | (d & 63);
    }
  }
}

// ---------------- CSR stage 4: per-tile counting sort -> row CSR ------------
__global__ __launch_bounds__(256) void row_sort_kernel(const int* __restrict__ tstart,
                                                       const int* __restrict__ epack,
                                                       int* __restrict__ starts,
                                                       int* __restrict__ srcs) {
  __shared__ int cnt[64];
  __shared__ int rbase[65];
  __shared__ int rofs[64];
  int t = threadIdx.x, b = blockIdx.x;
  int ts = tstart[b], te = tstart[b + 1];
  if (t < 64) cnt[t] = 0;
  __syncthreads();
  for (int i = ts + t; i < te; i += 256) atomicAdd(&cnt[epack[i] & 63], 1);
  __syncthreads();
  if (t == 0) {
    int a = 0;
    for (int r = 0; r < 64; r++) { rbase[r] = a; a += cnt[r]; }
    rbase[64] = a;
  }
  __syncthreads();
  if (t < 64) rofs[t] = ts + rbase[t];
  if (t <= 64) {
    int gr = b * 64 + t;
    if (gr <= N_NODES) starts[gr] = ts + rbase[t];
  }
  __syncthreads();
  for (int i = ts + t; i < te; i += 256) {
    int p = epack[i];
    int pos = atomicAdd(&rofs[p & 63], 1);
    srcs[pos] = p >> 6;
  }
}

// ---------------- gather (+ fused BN finalize-and-apply on inputs) ----------
// z[row] = h(row) + sum_{CSR[row]} h(src),  h(v) = BN ? relu(a*v+b) : v
// Scalar-path edge loop (row uniform via readfirstlane -> srcs via s_load).
template <int C, bool BN>
__global__ __launch_bounds__(256) void gather_kernel(const __bf16* __restrict__ h,
                                                     const float* __restrict__ accum,
                                                     const float* __restrict__ gamma,
                                                     const float* __restrict__ beta,
                                                     const int* __restrict__ starts,
                                                     const int* __restrict__ srcs,
                                                     __bf16* __restrict__ z) {
  const int lane = threadIdx.x & 63;
  const int row = __builtin_amdgcn_readfirstlane(blockIdx.x * 4 + (threadIdx.x >> 6));
  const int e0 = starts[row], e1 = starts[row + 1];

  if constexpr (C == 128) {
    float a0 = 0.f, a1 = 0.f, b0 = 0.f, b1 = 0.f;
    if constexpr (BN) {
      const int c0 = lane * 2, c1 = c0 + 1;
      const float invN = 1.f / (float)N_NODES;
      float m0 = accum[c0] * invN, m1 = accum[c1] * invN;
      float v0 = accum[HID + c0] * invN - m0 * m0;
      float v1 = accum[HID + c1] * invN - m1 * m1;
      a0 = gamma[c0] * rsqrtf(v0 + BN_EPS);
      a1 = gamma[c1] * rsqrtf(v1 + BN_EPS);
      b0 = beta[c0] - m0 * a0;
      b1 = beta[c1] - m1 * a1;
    }
#define ACCBN(vv, ss)                                                  \
    do {                                                               \
      if constexpr (BN) {                                              \
        ss.x += fmaxf(fmaf(a0, (float)(vv)[0], b0), 0.f);              \
        ss.y += fmaxf(fmaf(a1, (float)(vv)[1], b1), 0.f);              \
      } else {                                                         \
        ss.x += (float)(vv)[0];                                        \
        ss.y += (float)(vv)[1];                                        \
      }                                                                \
    } while (0)
    float2 s0 = {0.f, 0.f}, s1 = {0.f, 0.f}, s2 = {0.f, 0.f}, s3 = {0.f, 0.f};
    float2 s4 = {0.f, 0.f}, s5 = {0.f, 0.f}, s6 = {0.f, 0.f}, s7 = {0.f, 0.f};
    int e = e0;
    for (; e + 7 < e1; e += 8) {
      int i0 = srcs[e];      // uniform -> s_load
      int i1 = srcs[e + 1];
      int i2 = srcs[e + 2];
      int i3 = srcs[e + 3];
      int i4 = srcs[e + 4];
      int i5 = srcs[e + 5];
      int i6 = srcs[e + 6];
      int i7 = srcs[e + 7];
      bf16x2 v0 = *(const bf16x2*)(h + (size_t)i0 * 128 + lane * 2);
      bf16x2 v1 = *(const bf16x2*)(h + (size_t)i1 * 128 + lane * 2);
      bf16x2 v2 = *(const bf16x2*)(h + (size_t)i2 * 128 + lane * 2);
      bf16x2 v3 = *(const bf16x2*)(h + (size_t)i3 * 128 + lane * 2);
      bf16x2 v4 = *(const bf16x2*)(h + (size_t)i4 * 128 + lane * 2);
      bf16x2 v5 = *(const bf16x2*)(h + (size_t)i5 * 128 + lane * 2);
      bf16x2 v6 = *(const bf16x2*)(h + (size_t)i6 * 128 + lane * 2);
      bf16x2 v7 = *(const bf16x2*)(h + (size_t)i7 * 128 + lane * 2);
      ACCBN(v0, s0);
      ACCBN(v1, s1);
      ACCBN(v2, s2);
      ACCBN(v3, s3);
      ACCBN(v4, s4);
      ACCBN(v5, s5);
      ACCBN(v6, s6);
      ACCBN(v7, s7);
    }
    for (; e + 3 < e1; e += 4) {
      int i0 = srcs[e];
      int i1 = srcs[e + 1];
      int i2 = srcs[e + 2];
      int i3 = srcs[e + 3];
      bf16x2 v0 = *(const bf16x2*)(h + (size_t)i0 * 128 + lane * 2);
      bf16x2 v1 = *(const bf16x2*)(h + (size_t)i1 * 128 + lane * 2);
      bf16x2 v2 = *(const bf16x2*)(h + (size_t)i2 * 128 + lane * 2);
      bf16x2 v3 = *(const bf16x2*)(h + (size_t)i3 * 128 + lane * 2);
      ACCBN(v0, s0);
      ACCBN(v1, s1);
      ACCBN(v2, s2);
      ACCBN(v3, s3);
    }
    for (; e < e1; e++) {
      int i0 = srcs[e];
      bf16x2 vv = *(const bf16x2*)(h + (size_t)i0 * 128 + lane * 2);
      ACCBN(vv, s0);
    }
    bf16x2 sv = *(const bf16x2*)(h + (size_t)row * 128 + lane * 2);
    ACCBN(sv, s0);
    float tx = ((s0.x + s1.x) + (s2.x + s3.x)) + ((s4.x + s5.x) + (s6.x + s7.x));
    float ty = ((s0.y + s1.y) + (s2.y + s3.y)) + ((s4.y + s5.y) + (s6.y + s7.y));
    bf16x2 o = {(__bf16)tx, (__bf16)ty};
    *(bf16x2*)(z + (size_t)row * 128 + lane * 2) = o;
#undef ACCBN
  } else {  // C == 64 (layer 0, no BN)
    float s0 = 0.f, s1 = 0.f, s2 = 0.f, s3 = 0.f;
    float s4 = 0.f, s5 = 0.f, s6 = 0.f, s7 = 0.f;
    int e = e0;
    for (; e + 7 < e1; e += 8) {
      int i0 = srcs[e];
      int i1 = srcs[e + 1];
      int i2 = srcs[e + 2];
      int i3 = srcs[e + 3];
      int i4 = srcs[e + 4];
      int i5 = srcs[e + 5];
      int i6 = srcs[e + 6];
      int i7 = srcs[e + 7];
      s0 += (float)h[(size_t)i0 * 64 + lane];
      s1 += (float)h[(size_t)i1 * 64 + lane];
      s2 += (float)h[(size_t)i2 * 64 + lane];
      s3 += (float)h[(size_t)i3 * 64 + lane];
      s4 += (float)h[(size_t)i4 * 64 + lane];
      s5 += (float)h[(size_t)i5 * 64 + lane];
      s6 += (float)h[(size_t)i6 * 64 + lane];
      s7 += (float)h[(size_t)i7 * 64 + lane];
    }
    for (; e + 3 < e1; e += 4) {
      int i0 = srcs[e];
      int i1 = srcs[e + 1];
      int i2 = srcs[e + 2];
      int i3 = srcs[e + 3];
      s0 += (float)h[(size_t)i0 * 64 + lane];
      s1 += (float)h[(size_t)i1 * 64 + lane];
      s2 += (float)h[(size_t)i2 * 64 + lane];
      s3 += (float)h[(size_t)i3 * 64 + lane];
    }
    for (; e < e1; e++) {
      int i0 = srcs[e];
      s0 += (float)h[(size_t)i0 * 64 + lane];
    }
    s0 += (float)h[(size_t)row * 64 + lane];
    float tot = ((s0 + s1) + (s2 + s3)) + ((s4 + s5) + (s6 + s7));
    z[(size_t)row * 64 + lane] = (__bf16)tot;
  }
}

// ---------------- 4-wave MLP with LDS-staged weights ------------------------
// Block = 256 threads = 4 waves x 64 rows (M=64 per wave, the proven shape).
// W1+W2 staged ONCE per block into LDS with +8-elem padded row stride (272B:
// rows r and r+8 share a bank quad -> 2-way, free). Weight reads become
// ~12-cyc ds_read_b128 instead of per-wave 64KB L2 streams (100 -> 25 MB L2).
// One barrier after staging; compute/epilogue are wave-private (round-9 code).
template <int CIN>
__global__ __launch_bounds__(256, 1) void mlp_kernel(
    const __bf16* __restrict__ z, const __bf16* __restrict__ w1t,
    const float* __restrict__ b1, const __bf16* __restrict__ w2t,
    const float* __restrict__ b2, __bf16* __restrict__ u,
    float* __restrict__ part) {
  constexpr int CINP = CIN + 8;   // padded W1 row stride (elems)
  constexpr int TS = HID + 8;     // 136: padded W2/handoff stride
  __shared__ __align__(16) __bf16 w1s[128 * CINP];   // 34816B (CIN=128) / 18432B
  __shared__ __align__(16) __bf16 w2s[128 * TS];     // 34816B
  __shared__ __align__(16) __bf16 hsm[4 * 64 * TS];  // 69632B handoff

  const int tid = threadIdx.x;

  // cooperative weight staging (coalesced 16B chunks), padded LDS rows
  for (int i = tid; i < 128 * (CIN / 8); i += 256) {
    int r = i / (CIN / 8), c = i - r * (CIN / 8);
    *(bf16x8*)(w1s + r * CINP + c * 8) = *(const bf16x8*)(w1t + r * CIN + c * 8);
  }
  for (int i = tid; i < 128 * 16; i += 256) {
    int r = i >> 4, c = i & 15;
    *(bf16x8*)(w2s + r * TS + c * 8) = *(const bf16x8*)(w2t + r * HID + c * 8);
  }
  __syncthreads();  // the only barrier

  const int wid = tid >> 6;
  const int lane = tid & 63;
  const int l16 = lane & 15;
  const int quad = lane >> 4;
  const int wgid = blockIdx.x * 4 + wid;  // global wave id 0..1563
  const int rowbase = wgid * 64;
  const int nvalid = min(64, N_NODES - rowbase);  // may be <= 0 (tail wave)
  __bf16* sm = hsm + wid * 64 * TS;

  if (nvalid <= 0) {  // zero part row so reduce sees zeros
    float2 z2 = {0.f, 0.f};
    *(float2*)(part + (size_t)wgid * 256 + lane * 2) = z2;
    *(float2*)(part + (size_t)wgid * 256 + HID + lane * 2) = z2;
    return;
  }

  const f32x4 zero4 = {0.f, 0.f, 0.f, 0.f};
  f32x4 acc[8][4];

  // GEMM1: t1 = relu(z @ W1 + b1) -> handoff LDS tile (weights from LDS)
  {
#pragma unroll
    for (int ct = 0; ct < 8; ct++)
#pragma unroll
      for (int m = 0; m < 4; m++) acc[ct][m] = zero4;
#pragma unroll
    for (int ks = 0; ks < CIN / 32; ks++) {
      bf16x8 af[4];
#pragma unroll
      for (int m = 0; m < 4; m++) {
        int row = min(rowbase + m * 16 + l16, N_NODES - 1);
        af[m] = *(const bf16x8*)(z + (size_t)row * CIN + ks * 32 + quad * 8);
      }
#pragma unroll
      for (int ct = 0; ct < 8; ct++) {
        bf16x8 bfr = *(const bf16x8*)(w1s + (ct * 16 + l16) * CINP + ks * 32 + quad * 8);
#pragma unroll
        for (int m = 0; m < 4; m++)
          acc[ct][m] = __builtin_amdgcn_mfma_f32_16x16x32_bf16(af[m], bfr, acc[ct][m], 0, 0, 0);
      }
    }
#pragma unroll
    for (int ct = 0; ct < 8; ct++) {
      int col = ct * 16 + l16;
      float bias = b1[col];
#pragma unroll
      for (int m = 0; m < 4; m++)
#pragma unroll
        for (int r = 0; r < 4; r++) {
          float v = acc[ct][m][r] + bias;
          sm[(m * 16 + quad * 4 + r) * TS + col] = (__bf16)(v > 0.f ? v : 0.f);
        }
    }
  }

  // GEMM2: u = t1 @ W2 + b2 (in-wave LDS ordering via lgkmcnt; weights LDS)
  {
#pragma unroll
    for (int ct = 0; ct < 8; ct++)
#pragma unroll
      for (int m = 0; m < 4; m++) acc[ct][m] = zero4;
#pragma unroll
    for (int ks = 0; ks < HID / 32; ks++) {
      bf16x8 af[4];
#pragma unroll
      for (int m = 0; m < 4; m++)
        af[m] = *(const bf16x8*)(sm + (m * 16 + l16) * TS + ks * 32 + quad * 8);
#pragma unroll
      for (int ct = 0; ct < 8; ct++) {
        bf16x8 bfr = *(const bf16x8*)(w2s + (ct * 16 + l16) * TS + ks * 32 + quad * 8);
#pragma unroll
        for (int m = 0; m < 4; m++)
          acc[ct][m] = __builtin_amdgcn_mfma_f32_16x16x32_bf16(af[m], bfr, acc[ct][m], 0, 0, 0);
      }
    }
  }

  // epilogue: acc -> LDS (bf16), coalesced store + BN partials from LDS
#pragma unroll
  for (int ct = 0; ct < 8; ct++) {
    int col = ct * 16 + l16;
    float bias = b2[col];
#pragma unroll
    for (int m = 0; m < 4; m++)
#pragma unroll
      for (int r = 0; r < 4; r++)
        sm[(m * 16 + quad * 4 + r) * TS + col] = (__bf16)(acc[ct][m][r] + bias);
  }

  // coalesced bf16x8 store of valid rows
  for (int f = lane; f < nvalid * 16; f += 64) {
    int r = f >> 4, c8 = f & 15;
    bf16x8 v = *(const bf16x8*)(sm + r * TS + c8 * 8);
    *(bf16x8*)(u + (size_t)(rowbase + r) * HID + c8 * 8) = v;
  }

  // BN partials: lane owns columns 2*lane, 2*lane+1 -> coalesced part rows
  {
    float s0 = 0.f, q0 = 0.f, s1 = 0.f, q1 = 0.f;
    for (int r = 0; r < nvalid; r++) {
      bf16x2 v = *(const bf16x2*)(sm + r * TS + lane * 2);
      float f0 = (float)v[0], f1 = (float)v[1];
      s0 += f0; q0 += f0 * f0;
      s1 += f1; q1 += f1 * f1;
    }
    float2 sp = {s0, s1}, qp = {q0, q1};
    *(float2*)(part + (size_t)wgid * 256 + lane * 2) = sp;
    *(float2*)(part + (size_t)wgid * 256 + HID + lane * 2) = qp;
  }
}

// ---------------- part (PB x 256, coalesced) -> accum[256] via atomics ------
__global__ __launch_bounds__(256) void reduce_part_kernel(const float* __restrict__ part,
                                                          float* __restrict__ accum) {
  int t = threadIdx.x;
  float s = 0.f;
  for (int r = blockIdx.x; r < PB; r += gridDim.x)
    s += part[(size_t)r * 256 + t];
  atomicAdd(&accum[t], s);
}

// ---------------- BN finalize+apply + mean-pool accumulate (layer 2) --------
__global__ __launch_bounds__(128) void bn_apply_pool_kernel(const __bf16* __restrict__ u,
                                                            const float* __restrict__ accum,
                                                            const float* __restrict__ gamma,
                                                            const float* __restrict__ beta,
                                                            const int* __restrict__ batch,
                                                            float* __restrict__ pool) {
  int c = threadIdx.x;  // feature column
  int r0 = blockIdx.x * 64;
  if (r0 >= N_NODES) return;
  int rend = min(r0 + 64, N_NODES);
  const float invN = 1.f / (float)N_NODES;
  float mean = accum[c] * invN;
  float var = accum[HID + c] * invN - mean * mean;
  float a = gamma[c] * rsqrtf(var + BN_EPS);
  float b = beta[c] - mean * a;
  float accv = 0.f;
  int curg = -1;
  for (int r = r0; r < rend; r++) {
    int g = batch[r];
    if (g != curg) {
      if (curg >= 0) atomicAdd(&pool[curg * HID + c], accv);
      curg = g;
      accv = 0.f;
    }
    float v = (float)u[(size_t)r * HID + c];
    v = v * a + b;
    accv += (v > 0.f ? v : 0.f);
  }
  if (curg >= 0) atomicAdd(&pool[curg * HID + c], accv);
}

// ---------------- hg = pool/cnt; out = hg @ proj_w + proj_b -----------------
__global__ __launch_bounds__(128) void pool_proj_kernel(const float* __restrict__ pool,
                                                        const int* __restrict__ counts,
                                                        const float* __restrict__ pw,
                                                        const float* __restrict__ pb,
                                                        float* __restrict__ out) {
  int g = blockIdx.x;
  int c = threadIdx.x;
  __shared__ float hg[HID];
  float cnt = (float)max(counts[g], 1);
  hg[c] = pool[g * HID + c] / cnt;
  __syncthreads();
  float acc = pb[c];
#pragma unroll 8
  for (int k = 0; k < HID; k++) acc += hg[k] * pw[k * HID + c];
  out[g * HID + c] = acc;
}

// ============================================================================
extern "C" void kernel_launch(void* const* d_in, const int* in_sizes, int n_in,
                              void* d_out, int out_size, void* d_ws, size_t ws_size,
                              hipStream_t stream) {
  (void)in_sizes; (void)n_in; (void)out_size; (void)ws_size;
  const float* x = (const float*)d_in[0];
  const int* ei = (const int*)d_in[1];
  const int* batch = (const int*)d_in[2];
  const float* w1[3] = {(const float*)d_in[3], (const float*)d_in[9], (const float*)d_in[15]};
  const float* b1[3] = {(const float*)d_in[4], (const float*)d_in[10], (const float*)d_in[16]};
  const float* w2[3] = {(const float*)d_in[5], (const float*)d_in[11], (const float*)d_in[17]};
  const float* b2[3] = {(const float*)d_in[6], (const float*)d_in[12], (const float*)d_in[18]};
  const float* gm[3] = {(const float*)d_in[7], (const float*)d_in[13], (const float*)d_in[19]};
  const float* bt[3] = {(const float*)d_in[8], (const float*)d_in[14], (const float*)d_in[20]};
  const float* pw = (const float*)d_in[21];
  const float* pb = (const float*)d_in[22];
  float* out = (float*)d_out;

  // workspace carve
  char* ws = (char*)d_ws;
  __bf16* bufA = (__bf16*)ws;        ws += (size_t)N_NODES * HID * 2;   // 25.6 MB
  __bf16* bufB = (__bf16*)ws;        ws += (size_t)N_NODES * HID * 2;   // 25.6 MB
  __bf16* bufC = (__bf16*)ws;        ws += (size_t)N_NODES * HID * 2;   // 25.6 MB (z scratch)
  __bf16* z0 = (__bf16*)ws;          ws += (size_t)N_NODES * 64 * 2;    // 12.8 MB (layer-0 z)
  __bf16* xb = (__bf16*)ws;          ws += (size_t)N_NODES * 64 * 2;    // 12.8 MB
  int* srcs = (int*)ws;              ws += (size_t)N_EDGES * 4;         // 6.4 MB
  int* epack = (int*)ws;             ws += (size_t)N_EDGES * 4;         // 6.4 MB
  int* starts = (int*)ws;            ws += (size_t)(N_NODES + 1) * 4;
  int* tcnt = (int*)ws;              ws += NT * 4;
  int* tstart = (int*)ws;            ws += (NT + 1) * 4;
  int* gcursor = (int*)ws;           ws += NT * 4;
  ws = (char*)(((uintptr_t)ws + 63) & ~(uintptr_t)63);
  float* part = (float*)ws;          ws += (size_t)PB * 256 * 4;        // 1.6 MB
  __bf16* wt_all = (__bf16*)ws;      ws += 90112 * 2;
  ws = (char*)(((uintptr_t)ws + 63) & ~(uintptr_t)63);
  float* accum = (float*)ws;         ws += 3 * 256 * 4;                 // s,sq per layer
  float* pool = (float*)ws;          ws += N_GRAPHS * HID * 4;          // contiguous w/ accum
  int* counts = (int*)ws;            ws += N_GRAPHS * 4;                // and counts

  __bf16* w1t0 = wt_all;
  __bf16* w2t0 = wt_all + 8192;
  __bf16* w1t1 = wt_all + 24576;
  __bf16* w2t1 = wt_all + 40960;
  __bf16* w1t2 = wt_all + 57344;
  __bf16* w2t2 = wt_all + 73728;

  float* acc0 = accum;
  float* acc1 = accum + 256;
  float* acc2 = accum + 512;

  const int gat_blocks = (N_NODES + 3) / 4;  // 25000

  // zero accum + pool + counts (contiguous) and tcnt FIRST
  hipMemsetAsync(accum, 0, 3 * 256 * 4 + (size_t)N_GRAPHS * HID * 4 + N_GRAPHS * 4, stream);
  hipMemsetAsync(tcnt, 0, NT * 4, stream);

  // fused setup: x->bf16 (6250) + weights (352) + counts (7) + tile hist (391)
  setup_kernel<<<7000, 256, 0, stream>>>(x, xb, w1[0], w2[0], w1[1], w2[1],
                                         w1[2], w2[2], wt_all, batch, counts, ei, tcnt);

  // CSR build: tile scan -> tile-bucket scatter -> per-tile sort
  tile_scan_kernel<<<1, 256, 0, stream>>>(tcnt, tstart, gcursor);
  reorder2_kernel<<<RB, 256, 0, stream>>>(ei, gcursor, epack);
  row_sort_kernel<<<NT, 256, 0, stream>>>(tstart, epack, starts, srcs);

  // layer 0: gather(xb) -> z0; mlp64 -> bufA (u0) + part; reduce
  gather_kernel<64, false><<<gat_blocks, 256, 0, stream>>>(xb, nullptr, nullptr, nullptr,
                                                           starts, srcs, z0);
  mlp_kernel<64><<<MBLK, 256, 0, stream>>>(z0, w1t0, b1[0], w2t0, b2[0], bufA, part);
  reduce_part_kernel<<<128, 256, 0, stream>>>(part, acc0);

  // layer 1: BN(acc0)-relu-gather(u0) -> bufC; mlp -> bufB (u1); reduce
  gather_kernel<128, true><<<gat_blocks, 256, 0, stream>>>(bufA, acc0, gm[0], bt[0],
                                                           starts, srcs, bufC);
  mlp_kernel<128><<<MBLK, 256, 0, stream>>>(bufC, w1t1, b1[1], w2t1, b2[1], bufB, part);
  reduce_part_kernel<<<128, 256, 0, stream>>>(part, acc1);

  // layer 2: BN(acc1)-relu-gather(u1) -> bufC; mlp -> bufA (u2); reduce
  gather_kernel<128, true><<<gat_blocks, 256, 0, stream>>>(bufB, acc1, gm[1], bt[1],
                                                           starts, srcs, bufC);
  mlp_kernel<128><<<MBLK, 256, 0, stream>>>(bufC, w1t2, b1[2], w2t2, b2[2], bufA, part);
  reduce_part_kernel<<<128, 256, 0, stream>>>(part, acc2);

  bn_apply_pool_kernel<<<NT, 128, 0, stream>>>(bufA, acc2, gm[2], bt[2], batch, pool);

  pool_proj_kernel<<<N_GRAPHS, 128, 0, stream>>>(pool, counts, pw, pb, out);
}